// Round 1
// baseline (1453.058 us; speedup 1.0000x reference)
//
#include <hip/hip_runtime.h>
#include <hip/hip_bf16.h>
#include <stdint.h>

#define NPTS 4096
#define NNBR 16   // neighbors kept (reference keeps 17 incl. self, drops self)

// ---------------------------------------------------------------------------
// Kernel 1: exact 16-NN per point.
// One thread = one point. Whole batch's points staged in LDS as
// float4(x,y,z,|x|^2) = 64KB. All threads scan candidates in lockstep
// (uniform LDS address -> broadcast). 16-slot insertion ladder kept fully
// in registers (static unrolled indexing only).
// Strict '<' + ascending-q scan == jax.lax.top_k tie-break (lower index wins).
// ---------------------------------------------------------------------------
__global__ __launch_bounds__(256) void knn_kernel(const float* __restrict__ x0,
                                                  ushort* __restrict__ nbr) {
    const int b     = blockIdx.x >> 4;   // 16 chunks of 256 points per batch
    const int chunk = blockIdx.x & 15;
    const float* Xb = x0 + b * (NPTS * 3);

    __shared__ float4 pts[NPTS];         // 65536 B
    for (int i = threadIdx.x; i < NPTS; i += 256) {
        float x = Xb[i * 3 + 0];
        float y = Xb[i * 3 + 1];
        float z = Xb[i * 3 + 2];
        pts[i] = make_float4(x, y, z, x * x + y * y + z * z);
    }
    __syncthreads();

    const int p = chunk * 256 + threadIdx.x;
    const float4 me = pts[p];

    float ad[NNBR];
    int   ai[NNBR];
#pragma unroll
    for (int k = 0; k < NNBR; ++k) { ad[k] = 3.4e38f; ai[k] = 0; }

    for (int q = 0; q < NPTS; ++q) {
        const float4 c = pts[q];
        const float dot = me.x * c.x + me.y * c.y + me.z * c.z;
        const float d2  = (me.w + c.w) - 2.0f * dot;
        if (d2 < ad[NNBR - 1] && q != p) {
            float cd = d2;
            int   ci = q;
#pragma unroll
            for (int k = 0; k < NNBR; ++k) {
                const bool lt = cd < ad[k];
                const float od = ad[k]; const int oi = ai[k];
                ad[k] = lt ? cd : od;   ai[k] = lt ? ci : oi;
                cd    = lt ? od : cd;   ci    = lt ? oi : ci;
            }
        }
    }

    const uint base = (uint)(b * NPTS + p) * (uint)NNBR;
#pragma unroll
    for (int k = 0; k < NNBR; ++k) nbr[base + k] = (ushort)ai[k];
}

// ---------------------------------------------------------------------------
// Kernel 2: per-edge MLP + neighbor mean.
// One wave per point; lane = output channel o (D_OUT = 64 = wave width).
// h[o] = relu(b[o] + W[0:3,o].Xi + W[3:6,o].Xj + W[6:9,o].Vi + W[9:12,o].Vj)
// out[o] = (1/16) * sum_n h_n[o]
// ---------------------------------------------------------------------------
__global__ __launch_bounds__(256) void mlp_kernel(const float* __restrict__ x0,
                                                  const float* __restrict__ v0,
                                                  const float* __restrict__ W,
                                                  const float* __restrict__ bias,
                                                  const ushort* __restrict__ nbr,
                                                  float* __restrict__ out) {
    const int t    = threadIdx.x;
    const int wave = t >> 6;
    const int lane = t & 63;
    const int gp   = blockIdx.x * 4 + wave;   // global point id 0..16383
    const int b    = gp >> 12;
    const int p    = gp & (NPTS - 1);

    const float* Xb = x0 + b * (NPTS * 3);
    const float* Vb = v0 + b * (NPTS * 3);

    float w[12];
#pragma unroll
    for (int k = 0; k < 12; ++k) w[k] = W[k * 64 + lane];
    const float bb = bias[lane];

    const float xi0 = Xb[p * 3 + 0], xi1 = Xb[p * 3 + 1], xi2 = Xb[p * 3 + 2];
    const float vi0 = Vb[p * 3 + 0], vi1 = Vb[p * 3 + 1], vi2 = Vb[p * 3 + 2];

    const float base = bb + w[0] * xi0 + w[1] * xi1 + w[2] * xi2
                          + w[6] * vi0 + w[7] * vi1 + w[8] * vi2;

    __shared__ float nb[4][NNBR][8];   // [wave][neighbor][xj0..2, vj0..2, pad]
    if (lane < NNBR) {
        const int j = (int)nbr[(uint)gp * NNBR + lane];
        nb[wave][lane][0] = Xb[j * 3 + 0];
        nb[wave][lane][1] = Xb[j * 3 + 1];
        nb[wave][lane][2] = Xb[j * 3 + 2];
        nb[wave][lane][3] = Vb[j * 3 + 0];
        nb[wave][lane][4] = Vb[j * 3 + 1];
        nb[wave][lane][5] = Vb[j * 3 + 2];
    }
    __syncthreads();

    float acc = 0.0f;
#pragma unroll
    for (int n = 0; n < NNBR; ++n) {
        const float f0 = nb[wave][n][0];
        const float f1 = nb[wave][n][1];
        const float f2 = nb[wave][n][2];
        const float f3 = nb[wave][n][3];
        const float f4 = nb[wave][n][4];
        const float f5 = nb[wave][n][5];
        const float h = base + w[3] * f0 + w[4]  * f1 + w[5]  * f2
                             + w[9] * f3 + w[10] * f4 + w[11] * f5;
        acc += fmaxf(h, 0.0f);
    }

    out[(size_t)gp * 64 + lane] = acc * (1.0f / 16.0f);
}

// ---------------------------------------------------------------------------
// Kernel 3: passthrough copy of v0 into the output tail.
// ---------------------------------------------------------------------------
__global__ void copy_v_kernel(const float4* __restrict__ v, float4* __restrict__ o, int n) {
    const int i = blockIdx.x * blockDim.x + threadIdx.x;
    if (i < n) o[i] = v[i];
}

extern "C" void kernel_launch(void* const* d_in, const int* in_sizes, int n_in,
                              void* d_out, int out_size, void* d_ws, size_t ws_size,
                              hipStream_t stream) {
    const float* x0 = (const float*)d_in[0];   // (4, 12288)
    const float* v0 = (const float*)d_in[1];   // (4, 12288)
    const float* W  = (const float*)d_in[2];   // (12, 64)
    const float* bb = (const float*)d_in[3];   // (64,)
    float* out = (float*)d_out;                // 4*4096*64 floats, then 4*12288 floats (v0)

    ushort* nbr = (ushort*)d_ws;               // 16384 * 16 * 2B = 512 KB

    // 1) 16-NN selection: 64 blocks (B=4 x 16 chunks), 256 threads.
    knn_kernel<<<64, 256, 0, stream>>>(x0, nbr);

    // 2) MLP + mean: 4 points/block (4 waves), 16384 points -> 4096 blocks.
    mlp_kernel<<<4096, 256, 0, stream>>>(x0, v0, W, bb, nbr, out);

    // 3) v0 passthrough: 4*12288 floats = 12288 float4.
    const int n4 = (4 * NPTS * 3) / 4;
    copy_v_kernel<<<(n4 + 255) / 256, 256, 0, stream>>>(
        (const float4*)v0, (float4*)(out + 4 * NPTS * 64), n4);
}

// Round 2
// 259.453 us; speedup vs baseline: 5.6005x; 5.6005x over previous
//
#include <hip/hip_runtime.h>
#include <hip/hip_bf16.h>
#include <stdint.h>

#define NPTS 4096
#define NNBR 16     // neighbors kept (reference keeps 17 incl. self, drops self)
#define NSEG 8      // candidate segments per point
#define SEGLEN (NPTS / NSEG)
#define PTS_PER_BLK 32
#define BIGD 3.4e38f

// 16-slot sorted insertion ladder, fully register-resident (static unroll only).
__device__ __forceinline__ void ladder16(float (&ad)[NNBR], int (&ai)[NNBR],
                                         float cd, int ci) {
#pragma unroll
    for (int k = 0; k < NNBR; ++k) {
        const bool lt = cd < ad[k];
        const float od = ad[k]; const int oi = ai[k];
        ad[k] = lt ? cd : od;   ai[k] = lt ? ci : oi;
        cd    = lt ? od : cd;   ci    = lt ? oi : ci;
    }
}

// ---------------------------------------------------------------------------
// Kernel 1: exact 16-NN, candidate-split across 8 segments + in-block merge.
// Block = 256 threads = 32 points x 8 segments. Grid = 4 batches x 128 chunks
// = 512 blocks (2 blocks/CU, 2 waves/SIMD). All 4096 points staged in LDS as
// float4(x,y,z,|x|^2) = 64KB; after the scan the same LDS is reused for the
// partial-list merge (32KB partials + 8KB stage-2).
// Neighbor ORDER is irrelevant downstream (order-invariant mean), only the SET
// matters; ties are measure-zero with random normals.
// ---------------------------------------------------------------------------
__global__ __launch_bounds__(256) void knn_kernel(const float* __restrict__ x0,
                                                  ushort* __restrict__ nbr) {
    __shared__ __align__(16) unsigned char smem[65536];
    float4* pts = (float4*)smem;

    const int b     = blockIdx.x >> 7;     // 128 chunks per batch
    const int chunk = blockIdx.x & 127;
    const float* Xb = x0 + b * (NPTS * 3);

    for (int i = threadIdx.x; i < NPTS; i += 256) {
        const float x = Xb[3 * i + 0];
        const float y = Xb[3 * i + 1];
        const float z = Xb[3 * i + 2];
        pts[i] = make_float4(x, y, z, x * x + y * y + z * z);
    }
    __syncthreads();

    const int t   = threadIdx.x;
    const int seg = t >> 5;                // 0..7
    const int pt  = t & 31;                // 0..31
    const int p   = chunk * PTS_PER_BLK + pt;
    const float4 me = pts[p];

    float ad[NNBR];
    int   ai[NNBR];
#pragma unroll
    for (int k = 0; k < NNBR; ++k) { ad[k] = BIGD; ai[k] = 0; }

    const int q0 = seg * SEGLEN;
    for (int j = 0; j < SEGLEN; ++j) {
        const int q = q0 + j;
        const float4 c = pts[q];
        const float dot = me.x * c.x + me.y * c.y + me.z * c.z;
        const float d2  = (me.w + c.w) - 2.0f * dot;
        // Branchless: at 512 candidates/thread the wave-level insert branch
        // would be taken essentially every iteration anyway.
        const float cd = (q != p) ? d2 : BIGD;
        ladder16(ad, ai, cd, q);
    }
    __syncthreads();   // everyone done READING pts; safe to overwrite

    // Partial lists: part[pt][seg][16] as {d2, idx-bits} float2 = 32KB.
    float2* part = (float2*)smem;
    {
        float2* dst = part + (pt * NSEG + seg) * NNBR;
#pragma unroll
        for (int k = 0; k < NNBR; ++k)
            dst[k] = make_float2(ad[k], __int_as_float(ai[k]));
    }
    __syncthreads();

    // Merge stage 1: 64 threads, each merges 4 segment-lists (64 entries) -> 16.
    float2* m2 = (float2*)(smem + 32768);  // [32][2][16] = 8KB
    if (t < 64) {
        const int mpt = t & 31, half = t >> 5;
        float md[NNBR]; int mi[NNBR];
#pragma unroll
        for (int k = 0; k < NNBR; ++k) { md[k] = BIGD; mi[k] = 0; }
        const float2* src = part + (mpt * NSEG + half * 4) * NNBR;
        for (int e = 0; e < 64; ++e) {
            const float2 v = src[e];
            ladder16(md, mi, v.x, __float_as_int(v.y));
        }
        float2* dst = m2 + (mpt * 2 + half) * NNBR;
#pragma unroll
        for (int k = 0; k < NNBR; ++k)
            dst[k] = make_float2(md[k], __int_as_float(mi[k]));
    }
    __syncthreads();

    // Merge stage 2: 32 threads, each merges 2 lists (32 entries) -> final 16.
    if (t < 32) {
        float md[NNBR]; int mi[NNBR];
#pragma unroll
        for (int k = 0; k < NNBR; ++k) { md[k] = BIGD; mi[k] = 0; }
        const float2* src = m2 + t * 2 * NNBR;
        for (int e = 0; e < 32; ++e) {
            const float2 v = src[e];
            ladder16(md, mi, v.x, __float_as_int(v.y));
        }
        const uint base = (uint)(b * NPTS + chunk * PTS_PER_BLK + t) * (uint)NNBR;
#pragma unroll
        for (int k = 0; k < NNBR; ++k) nbr[base + k] = (ushort)mi[k];
    }
}

// ---------------------------------------------------------------------------
// Kernel 2: per-edge MLP + neighbor mean.
// One wave per point; lane = output channel o (D_OUT = 64 = wave width).
// ---------------------------------------------------------------------------
__global__ __launch_bounds__(256) void mlp_kernel(const float* __restrict__ x0,
                                                  const float* __restrict__ v0,
                                                  const float* __restrict__ W,
                                                  const float* __restrict__ bias,
                                                  const ushort* __restrict__ nbr,
                                                  float* __restrict__ out) {
    const int t    = threadIdx.x;
    const int wave = t >> 6;
    const int lane = t & 63;
    const int gp   = blockIdx.x * 4 + wave;   // global point id 0..16383
    const int b    = gp >> 12;
    const int p    = gp & (NPTS - 1);

    const float* Xb = x0 + b * (NPTS * 3);
    const float* Vb = v0 + b * (NPTS * 3);

    float w[12];
#pragma unroll
    for (int k = 0; k < 12; ++k) w[k] = W[k * 64 + lane];
    const float bb = bias[lane];

    const float xi0 = Xb[p * 3 + 0], xi1 = Xb[p * 3 + 1], xi2 = Xb[p * 3 + 2];
    const float vi0 = Vb[p * 3 + 0], vi1 = Vb[p * 3 + 1], vi2 = Vb[p * 3 + 2];

    const float base = bb + w[0] * xi0 + w[1] * xi1 + w[2] * xi2
                          + w[6] * vi0 + w[7] * vi1 + w[8] * vi2;

    __shared__ float nb[4][NNBR][8];
    if (lane < NNBR) {
        const int j = (int)nbr[(uint)gp * NNBR + lane];
        nb[wave][lane][0] = Xb[j * 3 + 0];
        nb[wave][lane][1] = Xb[j * 3 + 1];
        nb[wave][lane][2] = Xb[j * 3 + 2];
        nb[wave][lane][3] = Vb[j * 3 + 0];
        nb[wave][lane][4] = Vb[j * 3 + 1];
        nb[wave][lane][5] = Vb[j * 3 + 2];
    }
    __syncthreads();

    float acc = 0.0f;
#pragma unroll
    for (int n = 0; n < NNBR; ++n) {
        const float f0 = nb[wave][n][0];
        const float f1 = nb[wave][n][1];
        const float f2 = nb[wave][n][2];
        const float f3 = nb[wave][n][3];
        const float f4 = nb[wave][n][4];
        const float f5 = nb[wave][n][5];
        const float h = base + w[3] * f0 + w[4]  * f1 + w[5]  * f2
                             + w[9] * f3 + w[10] * f4 + w[11] * f5;
        acc += fmaxf(h, 0.0f);
    }

    out[(size_t)gp * 64 + lane] = acc * (1.0f / 16.0f);
}

// ---------------------------------------------------------------------------
// Kernel 3: passthrough copy of v0 into the output tail.
// ---------------------------------------------------------------------------
__global__ void copy_v_kernel(const float4* __restrict__ v, float4* __restrict__ o, int n) {
    const int i = blockIdx.x * blockDim.x + threadIdx.x;
    if (i < n) o[i] = v[i];
}

extern "C" void kernel_launch(void* const* d_in, const int* in_sizes, int n_in,
                              void* d_out, int out_size, void* d_ws, size_t ws_size,
                              hipStream_t stream) {
    const float* x0 = (const float*)d_in[0];   // (4, 12288)
    const float* v0 = (const float*)d_in[1];   // (4, 12288)
    const float* W  = (const float*)d_in[2];   // (12, 64)
    const float* bb = (const float*)d_in[3];   // (64,)
    float* out = (float*)d_out;

    ushort* nbr = (ushort*)d_ws;               // 16384 * 16 * 2B = 512 KB

    // 1) 16-NN: 512 blocks (4 batches x 128 chunks of 32 points), 256 threads.
    knn_kernel<<<512, 256, 0, stream>>>(x0, nbr);

    // 2) MLP + mean: 4 points/block (4 waves), 16384 points -> 4096 blocks.
    mlp_kernel<<<4096, 256, 0, stream>>>(x0, v0, W, bb, nbr, out);

    // 3) v0 passthrough: 4*12288 floats = 12288 float4.
    const int n4 = (4 * NPTS * 3) / 4;
    copy_v_kernel<<<(n4 + 255) / 256, 256, 0, stream>>>(
        (const float4*)v0, (float4*)(out + 4 * NPTS * 64), n4);
}

// Round 3
// 209.652 us; speedup vs baseline: 6.9308x; 1.2375x over previous
//
#include <hip/hip_runtime.h>
#include <hip/hip_bf16.h>
#include <stdint.h>

#define NPTS 4096
#define NNBR 16     // neighbors kept (reference keeps 17 incl. self, drops self)
#define NSEG 16     // candidate segments per point
#define PPB  16     // points per block
#define CAP  320    // per-point compacted-candidate capacity (stat headroom ~2x)
#define BIGD 3.4e38f

// ---------------------------------------------------------------------------
// Distance with operation order pinned to the numpy reference:
//   sq = (x*x + y*y) + z*z ;  dot = (px*cx + py*cy) + pz*cz
//   d2 = (sq_p + sq_q) - 2*dot      (2*dot == dot+dot, exact)
// Explicit *_rn intrinsics so hipcc's default fp-contract can't fuse anything:
// tau_kernel and select_kernel must produce BITWISE-identical d2.
// Bonus: self-distance is exactly 0.0 (sqnorm and dot collapse to same value).
// ---------------------------------------------------------------------------
__device__ __forceinline__ float sqnorm(float x, float y, float z) {
    return __fadd_rn(__fadd_rn(__fmul_rn(x, x), __fmul_rn(y, y)), __fmul_rn(z, z));
}
__device__ __forceinline__ float pair_d2(float px, float py, float pz, float sqp,
                                         float cx, float cy, float cz) {
    const float sqq = sqnorm(cx, cy, cz);
    const float dot = __fadd_rn(__fadd_rn(__fmul_rn(px, cx), __fmul_rn(py, cy)),
                                __fmul_rn(pz, cz));
    return __fsub_rn(__fadd_rn(sqp, sqq), __fadd_rn(dot, dot));
}

// Distance-only running-top-K slot update: 2 VALU (v_min/v_max), no VCC dep.
#define LADDER_MINMAX(AD, K, S)                                   \
    _Pragma("unroll")                                             \
    for (int k_ = 0; k_ < (K); ++k_) {                            \
        const float lo_ = fminf((S), AD[k_]);                     \
        (S) = fmaxf((S), AD[k_]);                                 \
        AD[k_] = lo_;                                             \
    }

// ---------------------------------------------------------------------------
// Kernel 1: per-point pruning threshold tau.
// Block = 256 threads = 16 points x 16 segments; each thread keeps the 17
// smallest d2 (self included, == 0.0 exactly) of its 256-candidate slice.
// tau_p = min over segments of that segment's 17th-smallest  >=  union's
// 17th-smallest  =>  all true 16-NN (excl self) have d2 <= tau_p.
// Candidate stream is float4-vectorized with a per-seg rotation so the 16
// segments' LDS reads land on distinct bank quads (<=2-way aliasing).
// ---------------------------------------------------------------------------
__global__ __launch_bounds__(256) void tau_kernel(const float* __restrict__ x0,
                                                  float* __restrict__ tau) {
    __shared__ float sx[NPTS], sy[NPTS], sz[NPTS];   // 48 KB -> 3 blocks/CU
    const int b     = blockIdx.x >> 8;               // 256 chunks per batch
    const int chunk = blockIdx.x & 255;
    const float* Xb = x0 + b * (NPTS * 3);
    const int t = threadIdx.x;

    for (int i = t; i < NPTS; i += 256) {
        sx[i] = Xb[3 * i + 0];
        sy[i] = Xb[3 * i + 1];
        sz[i] = Xb[3 * i + 2];
    }
    __syncthreads();

    const int seg = t & 15, pt = t >> 4;
    const int p = chunk * PPB + pt;
    const float px = sx[p], py = sy[p], pz = sz[p];
    const float sqp = sqnorm(px, py, pz);

    float ad[17];
#pragma unroll
    for (int k = 0; k < 17; ++k) ad[k] = BIGD;

    const int sb = seg << 8;                         // seg * 256
    for (int j = 0; j < 64; ++j) {
        const int r = ((j + seg) & 63) << 2;         // rotated, 16B-aligned
        const float4 cx4 = *(const float4*)&sx[sb + r];
        const float4 cy4 = *(const float4*)&sy[sb + r];
        const float4 cz4 = *(const float4*)&sz[sb + r];
        float s0 = pair_d2(px, py, pz, sqp, cx4.x, cy4.x, cz4.x);
        float s1 = pair_d2(px, py, pz, sqp, cx4.y, cy4.y, cz4.y);
        float s2 = pair_d2(px, py, pz, sqp, cx4.z, cy4.z, cz4.z);
        float s3 = pair_d2(px, py, pz, sqp, cx4.w, cy4.w, cz4.w);
        LADDER_MINMAX(ad, 17, s0)
        LADDER_MINMAX(ad, 17, s1)
        LADDER_MINMAX(ad, 17, s2)
        LADDER_MINMAX(ad, 17, s3)
    }
    __syncthreads();                                 // scan done; sx reusable

    float* sc = sx;                                  // 256-float scratch alias
    sc[t] = ad[16];                                  // this seg's 17th-smallest
    __syncthreads();

    if (t < PPB) {
        float m = sc[t * 16];
#pragma unroll
        for (int k = 1; k < 16; ++k) m = fminf(m, sc[t * 16 + k]);
        tau[b * NPTS + chunk * PPB + t] = m;
    }
}

// ---------------------------------------------------------------------------
// Kernel 2: exact top-16 via tau-pruned compaction.
// Phase 2: rescan (bitwise-identical d2), append candidates with d2 <= tau
//          into per-point LDS buffers (expected ~100-250 per point).
// Phase 3a: 4 threads/point ladder their stride-4 slice (distance-only).
// Phase 3b: 1 thread/point merges 4x16 sorted heads -> exact 16th-smallest.
// Phase 3c: marking pass emits the (exactly 16, no-ties assumption) indices.
// ---------------------------------------------------------------------------
__global__ __launch_bounds__(256) void select_kernel(const float* __restrict__ x0,
                                                     const float* __restrict__ tau,
                                                     ushort* __restrict__ nbr) {
    __shared__ float  sx[NPTS], sy[NPTS], sz[NPTS];  // 48 KB
    __shared__ ushort buf[PPB][CAP];                 // 10 KB
    __shared__ float  plist[PPB][64];                // 4 KB
    __shared__ float  t16[PPB];
    __shared__ float  tpt[PPB];
    __shared__ int    cnt[PPB];
    __shared__ int    cnt2[PPB];

    const int b     = blockIdx.x >> 8;
    const int chunk = blockIdx.x & 255;
    const float* Xb = x0 + b * (NPTS * 3);
    const int t = threadIdx.x;

    for (int i = t; i < NPTS; i += 256) {
        sx[i] = Xb[3 * i + 0];
        sy[i] = Xb[3 * i + 1];
        sz[i] = Xb[3 * i + 2];
    }
    if (t < PPB) {
        cnt[t] = 0; cnt2[t] = 0;
        tpt[t] = tau[b * NPTS + chunk * PPB + t];
    }
    __syncthreads();

    const int seg = t & 15, pt = t >> 4;
    const int p = chunk * PPB + pt;
    const float px = sx[p], py = sy[p], pz = sz[p];
    const float sqp = sqnorm(px, py, pz);
    const float tv = tpt[pt];

    const int sb = seg << 8;
    for (int j = 0; j < 64; ++j) {
        const int r = ((j + seg) & 63) << 2;
        const int q = sb + r;
        const float4 cx4 = *(const float4*)&sx[q];
        const float4 cy4 = *(const float4*)&sy[q];
        const float4 cz4 = *(const float4*)&sz[q];
        const float s0 = pair_d2(px, py, pz, sqp, cx4.x, cy4.x, cz4.x);
        const float s1 = pair_d2(px, py, pz, sqp, cx4.y, cy4.y, cz4.y);
        const float s2 = pair_d2(px, py, pz, sqp, cx4.z, cy4.z, cz4.z);
        const float s3 = pair_d2(px, py, pz, sqp, cx4.w, cy4.w, cz4.w);
        if (s0 <= tv && (q + 0) != p) { const int o = atomicAdd(&cnt[pt], 1); if (o < CAP) buf[pt][o] = (ushort)(q + 0); }
        if (s1 <= tv && (q + 1) != p) { const int o = atomicAdd(&cnt[pt], 1); if (o < CAP) buf[pt][o] = (ushort)(q + 1); }
        if (s2 <= tv && (q + 2) != p) { const int o = atomicAdd(&cnt[pt], 1); if (o < CAP) buf[pt][o] = (ushort)(q + 2); }
        if (s3 <= tv && (q + 3) != p) { const int o = atomicAdd(&cnt[pt], 1); if (o < CAP) buf[pt][o] = (ushort)(q + 3); }
    }
    __syncthreads();

    // Phase 3a: distance-only top-16 of each stride-4 slice (64 threads).
    if (t < 64) {
        const int p2 = t >> 2, sl = t & 3;
        const int n  = min(cnt[p2], CAP);
        const int pg = chunk * PPB + p2;
        const float ax = sx[pg], ay = sy[pg], az = sz[pg];
        const float sqa = sqnorm(ax, ay, az);
        float ad[16];
#pragma unroll
        for (int k = 0; k < 16; ++k) ad[k] = BIGD;
        for (int e = sl; e < n; e += 4) {
            const int q = buf[p2][e];
            float s = pair_d2(ax, ay, az, sqa, sx[q], sy[q], sz[q]);
            LADDER_MINMAX(ad, 16, s)
        }
#pragma unroll
        for (int k = 0; k < 16; ++k) plist[p2][sl * 16 + k] = ad[k];
    }
    __syncthreads();

    // Phase 3b: exact 16th-smallest distance among accepted (16 threads).
    if (t < PPB) {
        float ad[16];
#pragma unroll
        for (int k = 0; k < 16; ++k) ad[k] = BIGD;
        for (int e = 0; e < 64; ++e) {
            float s = plist[t][e];
            LADDER_MINMAX(ad, 16, s)
        }
        t16[t] = ad[15];
    }
    __syncthreads();

    // Phase 3c: emit the 16 indices with d2 <= 16th-smallest.
    if (t < 64) {
        const int p2 = t >> 2, sl = t & 3;
        const int n  = min(cnt[p2], CAP);
        const int pg = chunk * PPB + p2;
        const float ax = sx[pg], ay = sy[pg], az = sz[pg];
        const float sqa = sqnorm(ax, ay, az);
        const float th = t16[p2];
        const uint base = (uint)(b * NPTS + pg) * (uint)NNBR;
        for (int e = sl; e < n; e += 4) {
            const int q = buf[p2][e];
            const float s = pair_d2(ax, ay, az, sqa, sx[q], sy[q], sz[q]);
            if (s <= th) {
                const int o = atomicAdd(&cnt2[p2], 1);
                if (o < NNBR) nbr[base + o] = (ushort)q;
            }
        }
    }
}

// ---------------------------------------------------------------------------
// Kernel 3: per-edge MLP + neighbor mean. One wave per point; lane = channel.
// ---------------------------------------------------------------------------
__global__ __launch_bounds__(256) void mlp_kernel(const float* __restrict__ x0,
                                                  const float* __restrict__ v0,
                                                  const float* __restrict__ W,
                                                  const float* __restrict__ bias,
                                                  const ushort* __restrict__ nbr,
                                                  float* __restrict__ out) {
    const int t    = threadIdx.x;
    const int wave = t >> 6;
    const int lane = t & 63;
    const int gp   = blockIdx.x * 4 + wave;   // global point id 0..16383
    const int b    = gp >> 12;
    const int p    = gp & (NPTS - 1);

    const float* Xb = x0 + b * (NPTS * 3);
    const float* Vb = v0 + b * (NPTS * 3);

    float w[12];
#pragma unroll
    for (int k = 0; k < 12; ++k) w[k] = W[k * 64 + lane];
    const float bb = bias[lane];

    const float xi0 = Xb[p * 3 + 0], xi1 = Xb[p * 3 + 1], xi2 = Xb[p * 3 + 2];
    const float vi0 = Vb[p * 3 + 0], vi1 = Vb[p * 3 + 1], vi2 = Vb[p * 3 + 2];

    const float base = bb + w[0] * xi0 + w[1] * xi1 + w[2] * xi2
                          + w[6] * vi0 + w[7] * vi1 + w[8] * vi2;

    __shared__ float nb[4][NNBR][8];
    if (lane < NNBR) {
        const int j = (int)nbr[(uint)gp * NNBR + lane];
        nb[wave][lane][0] = Xb[j * 3 + 0];
        nb[wave][lane][1] = Xb[j * 3 + 1];
        nb[wave][lane][2] = Xb[j * 3 + 2];
        nb[wave][lane][3] = Vb[j * 3 + 0];
        nb[wave][lane][4] = Vb[j * 3 + 1];
        nb[wave][lane][5] = Vb[j * 3 + 2];
    }
    __syncthreads();

    float acc = 0.0f;
#pragma unroll
    for (int n = 0; n < NNBR; ++n) {
        const float h = base + w[3] * nb[wave][n][0] + w[4]  * nb[wave][n][1]
                             + w[5] * nb[wave][n][2] + w[9]  * nb[wave][n][3]
                             + w[10] * nb[wave][n][4] + w[11] * nb[wave][n][5];
        acc += fmaxf(h, 0.0f);
    }

    out[(size_t)gp * 64 + lane] = acc * (1.0f / 16.0f);
}

// ---------------------------------------------------------------------------
// Kernel 4: passthrough copy of v0 into the output tail.
// ---------------------------------------------------------------------------
__global__ void copy_v_kernel(const float4* __restrict__ v, float4* __restrict__ o, int n) {
    const int i = blockIdx.x * blockDim.x + threadIdx.x;
    if (i < n) o[i] = v[i];
}

extern "C" void kernel_launch(void* const* d_in, const int* in_sizes, int n_in,
                              void* d_out, int out_size, void* d_ws, size_t ws_size,
                              hipStream_t stream) {
    const float* x0 = (const float*)d_in[0];   // (4, 12288)
    const float* v0 = (const float*)d_in[1];   // (4, 12288)
    const float* W  = (const float*)d_in[2];   // (12, 64)
    const float* bb = (const float*)d_in[3];   // (64,)
    float* out = (float*)d_out;

    float*  tau = (float*)d_ws;                          // 16384 * 4B = 64 KB
    ushort* nbr = (ushort*)((char*)d_ws + NPTS * 4 * 4); // 16384 * 16 * 2B = 512 KB

    // 1) pruning thresholds: 1024 blocks (4 batches x 256 chunks of 16 points).
    tau_kernel<<<1024, 256, 0, stream>>>(x0, tau);

    // 2) exact top-16 under tau: same grid shape.
    select_kernel<<<1024, 256, 0, stream>>>(x0, tau, nbr);

    // 3) MLP + mean: 4 points/block (4 waves), 16384 points -> 4096 blocks.
    mlp_kernel<<<4096, 256, 0, stream>>>(x0, v0, W, bb, nbr, out);

    // 4) v0 passthrough: 4*12288 floats = 12288 float4.
    const int n4 = (4 * NPTS * 3) / 4;
    copy_v_kernel<<<(n4 + 255) / 256, 256, 0, stream>>>(
        (const float4*)v0, (float4*)(out + 4 * NPTS * 64), n4);
}

// Round 5
// 101.161 us; speedup vs baseline: 14.3638x; 2.0725x over previous
//
#include <hip/hip_runtime.h>
#include <hip/hip_bf16.h>
#include <stdint.h>

#define NPTS 4096
#define NNBR 16      // neighbors kept (reference keeps 17 incl. self, drops self)
#define PPB  16      // points per block
#define SEGPAD 260   // 256 cands/seg + 4-float pad, keeps float4 alignment (260%4==0)
#define CAP  88      // per-point accepted-candidate capacity (rank(tau) ~ 35-50)
#define BIGD 3.4e38f

// ---------------------------------------------------------------------------
// Distance with operation order pinned to the numpy reference (no FMA):
//   sq = (x*x + y*y) + z*z ; dot = (px*cx + py*cy) + pz*cz ; d2 = (sqp+sqq) - (dot+dot)
// Bitwise-identical across every use; self-distance is exactly +0.0.
// ---------------------------------------------------------------------------
__device__ __forceinline__ float sqnorm(float x, float y, float z) {
    return __fadd_rn(__fadd_rn(__fmul_rn(x, x), __fmul_rn(y, y)), __fmul_rn(z, z));
}
__device__ __forceinline__ float pair_d2(float px, float py, float pz, float sqp,
                                         float cx, float cy, float cz) {
    const float sqq = sqnorm(cx, cy, cz);
    const float dot = __fadd_rn(__fadd_rn(__fmul_rn(px, cx), __fmul_rn(py, cy)),
                                __fmul_rn(pz, cz));
    return __fsub_rn(__fadd_rn(sqp, sqq), __fadd_rn(dot, dot));
}

// depth-4 distance-only min/max ladder on named regs (2 VALU/slot, no VCC)
#define LAD4(S) { float lo_;                                      \
    lo_ = fminf(S, a0); S = fmaxf(S, a0); a0 = lo_;               \
    lo_ = fminf(S, a1); S = fmaxf(S, a1); a1 = lo_;               \
    lo_ = fminf(S, a2); S = fmaxf(S, a2); a2 = lo_;               \
    lo_ = fminf(S, a3); S = fmaxf(S, a3); a3 = lo_; }

// generic K-deep ladder over a register array (static unroll only)
#define LADK(AD, K, S)                                            \
    _Pragma("unroll")                                             \
    for (int k_ = 0; k_ < (K); ++k_) {                            \
        const float lo_ = fminf((S), AD[k_]);                     \
        (S) = fmaxf((S), AD[k_]);                                 \
        AD[k_] = lo_;                                             \
    }

// ---------------------------------------------------------------------------
// Fused exact 16-NN. Block = 256 thr = 16 points x 16 segments, grid = 1024.
//  scan1 : per-seg top-4 d2 (distance-only ladder), self included (d2==+0.0).
//  tau   : heads[pt][64] in LDS; 2 threads/pt LAD17 one 32-value half each;
//          tau = min(17th(H1), 17th(H2)) >= true d2_(17)  [subset order-stat].
//  scan2 : branchless {d2 <= tau} bitmask per 32-cand word; sparse extraction
//          appends (d2, idx) to per-point LDS list (atomic, CAP=88).
//  final : round-3-proven select — 2-slice LAD16 partials -> per-point LAD16
//          merge -> th = 16th smallest -> marking pass emits the 16 indices.
// ---------------------------------------------------------------------------
__global__ __launch_bounds__(256) void knn_kernel(const float* __restrict__ x0,
                                                  ushort* __restrict__ nbr) {
    __shared__ float sx[16 * SEGPAD], sy[16 * SEGPAD], sz[16 * SEGPAD]; // 49,920 B
    __shared__ __align__(16) unsigned char mbuf[PPB * CAP * 8];        // 11,264 B
    __shared__ float plist[PPB][32];                                   //  2,048 B
    __shared__ float ttau[PPB][2];
    __shared__ float t16[PPB];
    __shared__ int   cnt[PPB], cnt2[PPB];

    float2* list  = (float2*)mbuf;           // live from scan2 on
    float*  heads = (float*)mbuf;            // first 4 KB; dead before scan2

    const int b     = blockIdx.x >> 8;       // 256 chunks per batch
    const int chunk = blockIdx.x & 255;
    const float* Xb = x0 + b * (NPTS * 3);
    const int t = threadIdx.x;

    for (int i = t; i < NPTS; i += 256) {
        const int a = (i >> 8) * SEGPAD + (i & 255);
        sx[a] = Xb[3 * i + 0];
        sy[a] = Xb[3 * i + 1];
        sz[a] = Xb[3 * i + 2];
    }
    if (t < PPB) { cnt[t] = 0; cnt2[t] = 0; }
    __syncthreads();

    const int seg = t & 15, pt = t >> 4;
    const int p  = chunk * PPB + pt;                 // batch-local point id
    const int pa = (p >> 8) * SEGPAD + (p & 255);
    const float px = sx[pa], py = sy[pa], pz = sz[pa];
    const float sqp = sqnorm(px, py, pz);
    const int sb = seg * SEGPAD;

    // ---- scan1: per-seg top-4 (ascending a0..a3; self d2 == +0.0) ----
    float a0 = BIGD, a1 = BIGD, a2 = BIGD, a3 = BIGD;
    for (int j = 0; j < 64; ++j) {
        const int o = sb + 4 * j;
        const float4 cx4 = *(const float4*)&sx[o];
        const float4 cy4 = *(const float4*)&sy[o];
        const float4 cz4 = *(const float4*)&sz[o];
        float s0 = pair_d2(px, py, pz, sqp, cx4.x, cy4.x, cz4.x);
        float s1 = pair_d2(px, py, pz, sqp, cx4.y, cy4.y, cz4.y);
        float s2 = pair_d2(px, py, pz, sqp, cx4.z, cy4.z, cz4.z);
        float s3 = pair_d2(px, py, pz, sqp, cx4.w, cy4.w, cz4.w);
        LAD4(s0) LAD4(s1) LAD4(s2) LAD4(s3)
    }
    {
        float* hd = heads + pt * 64 + seg * 4;
        hd[0] = a0; hd[1] = a1; hd[2] = a2; hd[3] = a3;
    }
    __syncthreads();

    // ---- tau: 2 threads/pt, each LAD17 over one 32-value half of heads ----
    if (t < 32) {
        const int pm = t >> 1, half = t & 1;
        float ad[17];
#pragma unroll
        for (int k = 0; k < 17; ++k) ad[k] = BIGD;
        const float* src = heads + pm * 64 + half * 32;
        for (int e = 0; e < 32; ++e) {
            float s = src[e];
            LADK(ad, 17, s)
        }
        ttau[pm][half] = ad[16];             // this half's 17th-smallest
    }
    __syncthreads();                         // heads dead from here (list aliases)

    // ---- scan2: branchless accept-bitmask per 32-cand word + extraction ----
    const float tv = fminf(ttau[pt][0], ttau[pt][1]);
    for (int w = 0; w < 8; ++w) {
        uint m = 0;
#pragma unroll
        for (int jj = 0; jj < 8; ++jj) {
            const int o = sb + w * 32 + 4 * jj;
            const float4 cx4 = *(const float4*)&sx[o];
            const float4 cy4 = *(const float4*)&sy[o];
            const float4 cz4 = *(const float4*)&sz[o];
            const float s0 = pair_d2(px, py, pz, sqp, cx4.x, cy4.x, cz4.x);
            const float s1 = pair_d2(px, py, pz, sqp, cx4.y, cy4.y, cz4.y);
            const float s2 = pair_d2(px, py, pz, sqp, cx4.z, cy4.z, cz4.z);
            const float s3 = pair_d2(px, py, pz, sqp, cx4.w, cy4.w, cz4.w);
            m |= (s0 <= tv) ? (1u << (4 * jj + 0)) : 0u;
            m |= (s1 <= tv) ? (1u << (4 * jj + 1)) : 0u;
            m |= (s2 <= tv) ? (1u << (4 * jj + 2)) : 0u;
            m |= (s3 <= tv) ? (1u << (4 * jj + 3)) : 0u;
        }
        while (m) {                          // ~0.3 set bits/word/lane
            const int bpos = __ffs(m) - 1;
            m &= m - 1;
            const int ql = w * 32 + bpos;    // local idx within segment
            const int q  = seg * 256 + ql;   // batch-local candidate id
            if (q != p) {
                const int qa = sb + ql;
                const float d2 = pair_d2(px, py, pz, sqp, sx[qa], sy[qa], sz[qa]);
                const int o = atomicAdd(&cnt[pt], 1);
                if (o < CAP) list[pt * CAP + o] = make_float2(d2, __int_as_float(q));
            }
        }
    }
    __syncthreads();

    // ---- final 3a: 2 threads/pt, LAD16 over stride-2 slice of list ----
    if (t < 32) {
        const int p2 = t >> 1, sl = t & 1;
        const int n = min(cnt[p2], CAP);
        float ad[16];
#pragma unroll
        for (int k = 0; k < 16; ++k) ad[k] = BIGD;
        for (int e = sl; e < n; e += 2) {
            float s = list[p2 * CAP + e].x;
            LADK(ad, 16, s)
        }
#pragma unroll
        for (int k = 0; k < 16; ++k) plist[p2][sl * 16 + k] = ad[k];
    }
    __syncthreads();

    // ---- final 3b: 1 thread/pt, exact 16th-smallest among accepted ----
    if (t < PPB) {
        float ad[16];
#pragma unroll
        for (int k = 0; k < 16; ++k) ad[k] = BIGD;
        for (int e = 0; e < 32; ++e) {
            float s = plist[t][e];
            LADK(ad, 16, s)
        }
        t16[t] = ad[15];
    }
    __syncthreads();

    // ---- final 3c: marking pass emits the 16 indices with d2 <= th ----
    if (t < 64) {
        const int p2 = t >> 2, sl = t & 3;
        const int n = min(cnt[p2], CAP);
        const float th = t16[p2];
        const uint base = (uint)(b * NPTS + chunk * PPB + p2) * (uint)NNBR;
        for (int e = sl; e < n; e += 4) {
            const float2 v = list[p2 * CAP + e];
            if (v.x <= th) {
                const int o = atomicAdd(&cnt2[p2], 1);
                if (o < NNBR) nbr[base + o] = (ushort)__float_as_int(v.y);
            }
        }
    }
}

// ---------------------------------------------------------------------------
// MLP + neighbor mean (one wave per point, lane = output channel) with the
// v0 passthrough copy folded in (first 48 blocks copy one float4/thread).
// ---------------------------------------------------------------------------
__global__ __launch_bounds__(256) void mlp_kernel(const float* __restrict__ x0,
                                                  const float* __restrict__ v0,
                                                  const float* __restrict__ W,
                                                  const float* __restrict__ bias,
                                                  const ushort* __restrict__ nbr,
                                                  float* __restrict__ out) {
    const int t   = threadIdx.x;
    const int gid = blockIdx.x * 256 + t;
    if (gid < (4 * NPTS * 3) / 4) {                 // 12288 float4 copies
        ((float4*)(out + 4 * NPTS * 64))[gid] = ((const float4*)v0)[gid];
    }

    const int wave = t >> 6;
    const int lane = t & 63;
    const int gp   = blockIdx.x * 4 + wave;         // global point id 0..16383
    const int b    = gp >> 12;
    const int p    = gp & (NPTS - 1);

    const float* Xb = x0 + b * (NPTS * 3);
    const float* Vb = v0 + b * (NPTS * 3);

    float w[12];
#pragma unroll
    for (int k = 0; k < 12; ++k) w[k] = W[k * 64 + lane];
    const float bb = bias[lane];

    const float xi0 = Xb[p * 3 + 0], xi1 = Xb[p * 3 + 1], xi2 = Xb[p * 3 + 2];
    const float vi0 = Vb[p * 3 + 0], vi1 = Vb[p * 3 + 1], vi2 = Vb[p * 3 + 2];

    const float base = bb + w[0] * xi0 + w[1] * xi1 + w[2] * xi2
                          + w[6] * vi0 + w[7] * vi1 + w[8] * vi2;

    __shared__ float nb[4][NNBR][8];
    if (lane < NNBR) {
        const int j = (int)nbr[(uint)gp * NNBR + lane];
        nb[wave][lane][0] = Xb[j * 3 + 0];
        nb[wave][lane][1] = Xb[j * 3 + 1];
        nb[wave][lane][2] = Xb[j * 3 + 2];
        nb[wave][lane][3] = Vb[j * 3 + 0];
        nb[wave][lane][4] = Vb[j * 3 + 1];
        nb[wave][lane][5] = Vb[j * 3 + 2];
    }
    __syncthreads();

    float acc = 0.0f;
#pragma unroll
    for (int n = 0; n < NNBR; ++n) {
        const float h = base + w[3]  * nb[wave][n][0] + w[4]  * nb[wave][n][1]
                             + w[5]  * nb[wave][n][2] + w[9]  * nb[wave][n][3]
                             + w[10] * nb[wave][n][4] + w[11] * nb[wave][n][5];
        acc += fmaxf(h, 0.0f);
    }

    out[(size_t)gp * 64 + lane] = acc * (1.0f / 16.0f);
}

extern "C" void kernel_launch(void* const* d_in, const int* in_sizes, int n_in,
                              void* d_out, int out_size, void* d_ws, size_t ws_size,
                              hipStream_t stream) {
    const float* x0 = (const float*)d_in[0];   // (4, 12288)
    const float* v0 = (const float*)d_in[1];   // (4, 12288)
    const float* W  = (const float*)d_in[2];   // (12, 64)
    const float* bb = (const float*)d_in[3];   // (64,)
    float* out = (float*)d_out;

    ushort* nbr = (ushort*)d_ws;               // 16384 * 16 * 2B = 512 KB

    // 1) fused exact 16-NN: 1024 blocks (4 batches x 256 chunks of 16 points).
    knn_kernel<<<1024, 256, 0, stream>>>(x0, nbr);

    // 2) MLP + mean (+ folded v0 copy): 4 points/block, 4096 blocks.
    mlp_kernel<<<4096, 256, 0, stream>>>(x0, v0, W, bb, nbr, out);
}